// Round 3
// baseline (131.941 us; speedup 1.0000x reference)
//
#include <hip/hip_runtime.h>

#define BATCH_N 65536
#define SEQ_N   128
#define CH      8                 // rows per pipeline chunk
#define RB      (BATCH_N / 2)     // v4f elements per row

// Native clang vector types — accepted by __builtin_nontemporal_load/store.
typedef float v2f __attribute__((ext_vector_type(2)));
typedef float v4f __attribute__((ext_vector_type(4)));

// TWO batch elements per thread; 128-step sequential recurrence in registers.
// 32768 threads = 128-thread blocks x 256 = 1 block/CU, 2 waves/CU: still no
// TLP per SIMD, but each thread now carries TWO independent s/d-chains that
// interleave into each other's VALU/trans latency bubbles, and all global
// accesses are 16 B dwordx4 (load (t0,r0,t1,r1), store (s0,d0,s1,d1)) —
// half the VMEM instruction count of the 8 B/lane version.
// Depth-2 chunk pipeline (CH=8 rows): raw buffers reload the moment preC
// consumes them => always >=8 loads (8 KB/wave) in flight; load->use
// distance ~2 stepC + 1 preC >> ~900 cy HBM latency.
// Everything derivable from ratings alone (d-chain, success multiplier
// (11-d)*hb, failure multiplier w11*d^-w12) is precomputed off the s-chain's
// critical path; the branch flag rides in sign(M).
// Hot-phase step: 4 transcendentals (rcp, 1x log2, 2x exp2) + ~16 VALU.
__global__ __launch_bounds__(128, 1) void fsrs_kernel(
    const v4f* __restrict__ in,   // (SEQ, BATCH/2) of (t0,r0,t1,r1)
    const float* __restrict__ w,  // 17 weights
    v4f*       __restrict__ out)  // (SEQ, BATCH/2) of (s0,d0,s1,d1), then final
{
    const int g = blockIdx.x * 128 + threadIdx.x;   // batch-pair index

    const float w0 = w[0], w1 = w[1], w2 = w[2], w3 = w[3];
    const float w4 = w[4], w5 = w[5], w6 = w[6], w7 = w[7];
    const float w9 = w[9], w11 = w[11], w12 = w[12], w13 = w[13];
    const float w15 = w[15], w16 = w[16];
    constexpr float LOG2E = 1.44269504088896340736f;
    const float w8l  = w[8]  * LOG2E;   // exp(w8)*s^-w9 = exp2(w8l - w9*log2 s)
    const float w10l = w[10] * LOG2E;
    const float w14l = w[14] * LOG2E;
    const float omw7   = 1.0f - w7;
    const float omw7w6 = omw7 * w6;
    const float dc0    = w7 * w4 + 3.0f * omw7w6;

    const v4f* ip = in  + g;
    v4f*       op = out + g;

    float s0 = 0.01f, s1 = 0.01f;       // stability states (2 chains)
    float dp0 = 1.0f, dp1 = 1.0f;       // d running ahead (precompute timing)

    v4f rawA[CH], rawB[CH];
    v2f tA[CH], dA[CH], mA[CH];   // t, new-d (output), merged multiplier
    v2f tB[CH], dB[CH], mB[CH];

    auto loadC = [&](v4f* raw, int base) {
#pragma unroll
        for (int i = 0; i < CH; ++i)
            raw[i] = __builtin_nontemporal_load(&ip[(base + i) * RB]);
    };

    // Per-element precompute. Uses/updates dpre (old d on entry).
    // M = success ? (11-d_old)*hb : -(w11*d_old^-w12); sign(M) = branch.
    auto preRow = [&](float rating, float& dpre, float& D, float& M) {
        const float hb = (rating == 2.0f) ? w15
                       : ((rating == 4.0f) ? w16 : 1.0f);
        const float eh = (11.0f - dpre) * hb;
        const float m2 = w11 * __builtin_amdgcn_exp2f(
                             -w12 * __builtin_amdgcn_logf(dpre));
        M = (rating > 1.0f) ? eh : -m2;
        const float nd = __builtin_fmaf(omw7, dpre,
                          __builtin_fmaf(-omw7w6, rating, dc0));
        dpre = fminf(fmaxf(nd, 1.0f), 10.0f);
        D = dpre;
    };

    auto preC = [&](const v4f* raw, v2f* T, v2f* D, v2f* M, int lo) {
#pragma unroll
        for (int i = 0; i < CH; ++i) {
            if (i < lo) continue;
            v2f t; t.x = raw[i].x; t.y = raw[i].z;
            float Dx, Mx, Dy, My;
            preRow(raw[i].y, dp0, Dx, Mx);
            preRow(raw[i].w, dp1, Dy, My);
            T[i] = t;
            v2f d; d.x = Dx; d.y = Dy; D[i] = d;
            v2f m; m.x = Mx; m.y = My; M[i] = m;
        }
    };

    // Per-element hot step: s-recurrence only; branch known up front (sign
    // of M) so a single log serves s^-w9 (success) and (s+1)^w13 (failure);
    // clamps split per-branch (success can't underflow S_MIN; failure can't
    // exceed s<=S_MAX).
    auto stepRow = [&](float tt, float ms, float& s) {
        const bool  sel = ms > 0.0f;                    // success?
        const float q   = __builtin_fmaf(9.0f, s, tt);  // 9s + t
        const float omr = tt * __builtin_amdgcn_rcpf(q);// 1 - r
        const float e   = __builtin_amdgcn_exp2f(omr * (sel ? w10l : w14l));
        const float ls  = __builtin_amdgcn_logf(sel ? s : (s + 1.0f));
        const float aa  = sel ? __builtin_fmaf(-w9, ls, w8l) : (w13 * ls);
        const float A   = __builtin_amdgcn_exp2f(aa);
        const float Af  = sel ? A          : (A - 1.0f);
        const float Ef  = sel ? (e - 1.0f) : e;
        const float m   = sel ? (ms * s)   : (-ms);
        const float P   = Af * Ef * m;
        const float su  = fminf(s + P, 36500.0f);
        const float fl  = fmaxf(fminf(P, s), 0.01f);
        s = sel ? su : fl;
    };

    auto stepC = [&](const v2f* T, const v2f* D, const v2f* M,
                     int base, int lo) {
#pragma unroll
        for (int i = 0; i < CH; ++i) {
            if (i < lo) continue;
            stepRow(T[i].x, M[i].x, s0);
            stepRow(T[i].y, M[i].y, s1);
            v4f o; o.x = s0; o.y = D[i].x; o.z = s1; o.w = D[i].y;
            __builtin_nontemporal_store(o, &op[(base + i) * RB]);
        }
    };

    // ---- prologue: chunks ch0 (rows 0..7), ch1 (8..15) ----
    loadC(rawA, 0);
    loadC(rawB, CH);

    const float r00 = rawA[0].y, r01 = rawA[0].w;
    {   // row 0: _first_step (d0 comes from rating only)
        const float d00 = fminf(fmaxf(
            __builtin_fmaf(-w5, r00 - 3.0f, w4), 1.0f), 10.0f);
        const float d01 = fminf(fmaxf(
            __builtin_fmaf(-w5, r01 - 3.0f, w4), 1.0f), 10.0f);
        dp0 = d00; dp1 = d01;
        v2f t; t.x = rawA[0].x; t.y = rawA[0].z; tA[0] = t;
        v2f d; d.x = d00; d.y = d01; dA[0] = d;
        v2f m; m.x = 1.0f; m.y = 1.0f; mA[0] = m;
    }
    preC(rawA, tA, dA, mA, 1);     // ch0 — rawA free after this
    loadC(rawA, 2 * CH);           // ch2 in flight

    {   // step row 0 (special): s0 from weight table
        const float ws0 = (r00 < 2.5f) ? ((r00 < 1.5f) ? w0 : w1)
                                       : ((r00 < 3.5f) ? w2 : w3);
        const float ws1 = (r01 < 2.5f) ? ((r01 < 1.5f) ? w0 : w1)
                                       : ((r01 < 3.5f) ? w2 : w3);
        const float n0 = (r00 >= 1.0f && r00 <= 4.0f) ? ws0 : 1.0f;
        const float n1 = (r01 >= 1.0f && r01 <= 4.0f) ? ws1 : 1.0f;
        s0 = fminf(fmaxf(n0, 0.01f), 36500.0f);
        s1 = fminf(fmaxf(n1, 0.01f), 36500.0f);
        v4f o; o.x = s0; o.y = dA[0].x; o.z = s1; o.w = dA[0].y;
        __builtin_nontemporal_store(o, &op[0]);
    }
    stepC(tA, dA, mA, 0, 1);       // ch0 rows 1..7
    preC(rawB, tB, dB, mB, 0);     // ch1 — rawB free after this
    loadC(rawB, 3 * CH);           // ch3 in flight
    // steady-state invariant at loop top: tB = pre'd ch(2c+1);
    // rawA = ch(2c+2), rawB = ch(2c+3) in flight (loaded >=1 phase ago).

    // ---- main: iter c handles ch(2c+1), ch(2c+2); loads ch(2c+4), ch(2c+5)
#pragma unroll 1
    for (int c = 0; c < 6; ++c) {
        stepC(tB, dB, mB, CH * (2 * c + 1), 0);   // ch 2c+1
        preC(rawA, tA, dA, mA, 0);                // ch 2c+2 — rawA free
        loadC(rawA, CH * (2 * c + 4));            // ch 2c+4
        stepC(tA, dA, mA, CH * (2 * c + 2), 0);   // ch 2c+2
        preC(rawB, tB, dB, mB, 0);                // ch 2c+3 — rawB free
        loadC(rawB, CH * (2 * c + 5));            // ch 2c+5
    }

    // ---- tail: ch13, ch14, ch15 (all loads already in flight) ----
    stepC(tB, dB, mB, 13 * CH, 0); // ch13
    preC(rawA, tA, dA, mA, 0);     // ch14
    stepC(tA, dA, mA, 14 * CH, 0); // ch14
    preC(rawB, tB, dB, mB, 0);     // ch15
    stepC(tB, dB, mB, 15 * CH, 0); // ch15

    // final_state, appended after the (SEQ, BATCH) outputs.
    {
        v4f o; o.x = s0; o.y = dB[CH - 1].x; o.z = s1; o.w = dB[CH - 1].y;
        op[SEQ_N * RB] = o;
    }
}

extern "C" void kernel_launch(void* const* d_in, const int* in_sizes, int n_in,
                              void* d_out, int out_size, void* d_ws, size_t ws_size,
                              hipStream_t stream) {
    const v4f*   in = (const v4f*)d_in[0];   // (128, 65536, 2) f32
    const float* w  = (const float*)d_in[1]; // (17,) f32
    v4f* out = (v4f*)d_out;                  // 128*65536 + 65536 float2
    fsrs_kernel<<<RB / 128, 128, 0, stream>>>(in, w, out);
}

// Round 4
// 113.678 us; speedup vs baseline: 1.1607x; 1.1607x over previous
//
#include <hip/hip_runtime.h>

#define BATCH_N 65536
#define SEQ_N   128

// Native clang vector type — accepted by __builtin_nontemporal_load/store.
typedef float v2f __attribute__((ext_vector_type(2)));

// One thread per batch element; 128-step sequential recurrence in registers.
// 65536 threads = 1024 waves = exactly 1 wave per SIMD chip-wide: all 4 SIMDs
// per CU issue, but there is NO TLP — every vmcnt stall is exposed. So the
// load stream is paced: the 16 loads of chunk k+2 are issued 4-at-a-time
// interleaved between groups of 4 step-rows of chunk k, keeping the VMEM
// queue at a steady ~16 outstanding instead of burst-then-drain (the R1
// version clustered all 16 loads, then drained to zero during preC).
// Everything derivable from ratings alone (d-chain, success multiplier
// (11-d)*hb, failure multiplier w11*d^-w12) is precomputed in preC, off the
// s-chain's critical path; the branch flag rides in sign(M).
// Hot-phase step: 4 transcendentals (rcp, 1x log2, 2x exp2) + ~16 VALU.
__global__ __launch_bounds__(256, 1) void fsrs_kernel(
    const v2f* __restrict__ in,   // (SEQ, BATCH) of (t, rating)
    const float* __restrict__ w,  // 17 weights
    v2f*       __restrict__ out)  // (SEQ, BATCH) of (s, d) then (BATCH) final
{
    const int b = blockIdx.x * 256 + threadIdx.x;

    const float w0 = w[0], w1 = w[1], w2 = w[2], w3 = w[3];
    const float w4 = w[4], w5 = w[5], w6 = w[6], w7 = w[7];
    const float w9 = w[9], w11 = w[11], w12 = w[12], w13 = w[13];
    const float w15 = w[15], w16 = w[16];
    constexpr float LOG2E = 1.44269504088896340736f;
    const float w8l  = w[8]  * LOG2E;   // exp(w8)*s^-w9 = exp2(w8l - w9*log2 s)
    const float w10l = w[10] * LOG2E;
    const float w14l = w[14] * LOG2E;
    const float omw7   = 1.0f - w7;
    const float omw7w6 = omw7 * w6;
    const float dc0    = w7 * w4 + 3.0f * omw7w6;

    const v2f* ip = in  + b;
    v2f*       op = out + b;

    float s = 0.01f;       // stability state
    float dpre = 1.0f;     // d running ahead (precompute timing)

    v2f rawA[16], rawB[16];
    float tX[16], dX[16], mX[16];   // t, new-d (output), merged multiplier
    float tY[16], dY[16], mY[16];

    // Prologue-only burst load of a 16-row chunk.
    auto loadC = [&](v2f* raw, int base) {
#pragma unroll
        for (int i = 0; i < 16; ++i) raw[i] = ip[(base + i) * BATCH_N];
    };

    // Precompute rows [lo,16) of a chunk. Uses/updates dpre (old d on entry
    // to each row). M[i] = success ? (11-d_old)*hb : -(w11*d_old^-w12);
    // sign(M) encodes the branch ((11-d)>=1>0 and w11*d^-w12>0 always).
    auto preC = [&](const v2f* raw, float* T, float* D, float* M, int lo) {
#pragma unroll
        for (int i = 0; i < 16; ++i) {
            if (i < lo) continue;
            const float tt = raw[i].x, rating = raw[i].y;
            const float hb = (rating == 2.0f) ? w15
                           : ((rating == 4.0f) ? w16 : 1.0f);
            const float eh = (11.0f - dpre) * hb;
            const float m2 = w11 * __builtin_amdgcn_exp2f(
                                 -w12 * __builtin_amdgcn_logf(dpre));
            M[i] = (rating > 1.0f) ? eh : -m2;
            const float nd = __builtin_fmaf(omw7, dpre,
                              __builtin_fmaf(-omw7w6, rating, dc0));
            dpre = fminf(fmaxf(nd, 1.0f), 10.0f);
            T[i] = tt;
            D[i] = dpre;
        }
    };

    // One hot step: s-recurrence + store. Branch known up front (sign of M)
    // so a single log serves s^-w9 (success) and (s+1)^w13 (failure); clamps
    // split per-branch (success can't underflow S_MIN; failure can't exceed
    // s<=S_MAX).
    auto stepRow = [&](float tt, float ms, float dd, int row) {
        const bool  sel = ms > 0.0f;                    // success?
        const float q   = __builtin_fmaf(9.0f, s, tt);  // 9s + t
        const float omr = tt * __builtin_amdgcn_rcpf(q);// 1 - r
        const float e   = __builtin_amdgcn_exp2f(omr * (sel ? w10l : w14l));
        const float ls  = __builtin_amdgcn_logf(sel ? s : (s + 1.0f));
        const float aa  = sel ? __builtin_fmaf(-w9, ls, w8l) : (w13 * ls);
        const float A   = __builtin_amdgcn_exp2f(aa);
        const float Af  = sel ? A          : (A - 1.0f);
        const float Ef  = sel ? (e - 1.0f) : e;
        const float m   = sel ? (ms * s)   : (-ms);
        const float P   = Af * Ef * m;
        const float su  = fminf(s + P, 36500.0f);
        const float fl  = fmaxf(fminf(P, s), 0.01f);
        s = sel ? su : fl;
        v2f o; o.x = s; o.y = dd;
        __builtin_nontemporal_store(o, &op[row * BATCH_N]);
    };

    // Step chunk at `base` (rows [lo,16)) while pacing the 16 loads of a
    // future chunk into `raw`, 4 loads per 4 step-rows.
    auto phase = [&](const float* T, const float* D, const float* M,
                     int base, int lo, v2f* raw, int loadBase, bool doLoad) {
#pragma unroll
        for (int q = 0; q < 4; ++q) {
            if (doLoad) {
#pragma unroll
                for (int j = 0; j < 4; ++j)
                    raw[4 * q + j] = ip[(loadBase + 4 * q + j) * BATCH_N];
            }
#pragma unroll
            for (int j = 0; j < 4; ++j) {
                const int i = 4 * q + j;
                if (i < lo) continue;
                stepRow(T[i], M[i], D[i], base + i);
            }
        }
    };

    // ---- prologue: chunks ch0 (rows 0..15), ch1 (16..31) ----
    loadC(rawA, 0);
    loadC(rawB, 16);

    const float r0 = rawA[0].y;
    {   // row 0: _first_step (d0 comes from rating only)
        const float d0 = fminf(fmaxf(
            __builtin_fmaf(-w5, r0 - 3.0f, w4), 1.0f), 10.0f);
        dpre = d0;
        tX[0] = rawA[0].x; dX[0] = d0; mX[0] = 1.0f;
    }
    preC(rawA, tX, dX, mX, 1);     // ch0 -> X; rawA free

    {   // step row 0 (special): s0 from weight table
        const float wsel = (r0 < 2.5f) ? ((r0 < 1.5f) ? w0 : w1)
                                       : ((r0 < 3.5f) ? w2 : w3);
        const float ns = (r0 >= 1.0f && r0 <= 4.0f) ? wsel : 1.0f;
        s = fminf(fmaxf(ns, 0.01f), 36500.0f);
        v2f o; o.x = s; o.y = dX[0];
        __builtin_nontemporal_store(o, &op[0]);
    }
    phase(tX, dX, mX, 0, 1, rawA, 32, true);    // step ch0 (1..15) | load ch2
    preC(rawB, tY, dY, mY, 0);                  // ch1 -> Y; rawB free
    phase(tY, dY, mY, 16, 0, rawB, 48, true);   // step ch1 | load ch3

    // ---- main: c=0 -> ch2,ch3 (loads ch4,ch5); c=1 -> ch4,ch5 (ch6,ch7)
#pragma unroll 1
    for (int c = 0; c < 2; ++c) {
        preC(rawA, tX, dX, mX, 0);                              // ch 2c+2
        phase(tX, dX, mX, 32 * (c + 1), 0,
              rawA, 32 * (c + 2), true);                        // load ch 2c+4
        preC(rawB, tY, dY, mY, 0);                              // ch 2c+3
        phase(tY, dY, mY, 32 * (c + 1) + 16, 0,
              rawB, 32 * (c + 2) + 16, true);                   // load ch 2c+5
    }

    // ---- tail: ch6 (rawA), ch7 (rawB) — all loads already in flight ----
    preC(rawA, tX, dX, mX, 0);
    phase(tX, dX, mX, 96, 0, rawA, 0, false);
    preC(rawB, tY, dY, mY, 0);
    phase(tY, dY, mY, 112, 0, rawB, 0, false);

    // final_state, appended after the (SEQ, BATCH) outputs.
    {
        v2f o; o.x = s; o.y = dY[15];
        op[SEQ_N * BATCH_N] = o;
    }
}

extern "C" void kernel_launch(void* const* d_in, const int* in_sizes, int n_in,
                              void* d_out, int out_size, void* d_ws, size_t ws_size,
                              hipStream_t stream) {
    const v2f*   in = (const v2f*)d_in[0];   // (128, 65536, 2) f32
    const float* w  = (const float*)d_in[1]; // (17,) f32
    v2f* out = (v2f*)d_out;                  // 128*65536 + 65536 float2
    fsrs_kernel<<<BATCH_N / 256, 256, 0, stream>>>(in, w, out);
}

// Round 5
// 111.778 us; speedup vs baseline: 1.1804x; 1.0170x over previous
//
#include <hip/hip_runtime.h>

#define BATCH_N 65536
#define SEQ_N   128

// Native clang vector type — accepted by __builtin_nontemporal_load/store.
typedef float v2f __attribute__((ext_vector_type(2)));

// One thread per batch element; 128-step sequential recurrence in registers.
// 65536 threads = 1024 waves = exactly 1 wave per SIMD chip-wide: no TLP, so
// ALL latency hiding must come from ILP inside the one wave. This version
// fuses the three independent instruction streams at ROW granularity:
//   per row i of a 16-row phase:
//     - 1 global load of chunk k+2 row i      (memory stream)
//     - preRow of chunk k+1 row i             (d-chain: ~10 VALU + 2 trans)
//     - stepRow of chunk k row i              (s-chain: ~18 VALU + 4 trans + NT store)
// The s-chain's serial dependency spine (~56 cy/row) is filled with the
// d-chain's and load stream's instructions and vice versa — previously these
// ran as separate serial sections (preC phase, then step phase) and each
// chain's bubbles were exposed (R3 counters: VALUBusy 21%, 75%+ stall).
// Load->consume distance stays one full phase (~1900 cy >> ~900 cy HBM).
// stepRow math: P = (exp2(aa+x) - exp2(sel?aa:x)) * m merges the success/
// failure algebra — success: A*e - A = A(e-1); failure: A*e - e = e(A-1).
__global__ __launch_bounds__(256, 1) void fsrs_kernel(
    const v2f* __restrict__ in,   // (SEQ, BATCH) of (t, rating)
    const float* __restrict__ w,  // 17 weights
    v2f*       __restrict__ out)  // (SEQ, BATCH) of (s, d) then (BATCH) final
{
    const int b = blockIdx.x * 256 + threadIdx.x;

    const float w0 = w[0], w1 = w[1], w2 = w[2], w3 = w[3];
    const float w4 = w[4], w5 = w[5], w6 = w[6], w7 = w[7];
    const float w9 = w[9], w11 = w[11], w12 = w[12], w13 = w[13];
    const float w15 = w[15], w16 = w[16];
    constexpr float LOG2E = 1.44269504088896340736f;
    const float w8l  = w[8]  * LOG2E;   // exp(w8)*s^-w9 = exp2(w8l - w9*log2 s)
    const float w10l = w[10] * LOG2E;
    const float w14l = w[14] * LOG2E;
    const float omw7   = 1.0f - w7;
    const float omw7w6 = omw7 * w6;
    const float dc0    = w7 * w4 + 3.0f * omw7w6;

    const v2f* ip = in  + b;
    v2f*       op = out + b;

    float s = 0.01f;       // stability state (serial s-chain)
    float dpre = 1.0f;     // d running ahead (serial d-chain, 1 chunk early)

    v2f rawA[16], rawB[16];
    float tX[16], dX[16], mX[16];   // t, new-d (output), merged multiplier
    float tY[16], dY[16], mY[16];

    // Prologue-only burst load of a 16-row chunk.
    auto loadC = [&](v2f* raw, int base) {
#pragma unroll
        for (int i = 0; i < 16; ++i) raw[i] = ip[(base + i) * BATCH_N];
    };

    // d-chain row: uses/updates dpre (old d on entry). M = success ?
    // (11-d_old)*hb : -(w11*d_old^-w12); sign(M) encodes the branch
    // ((11-d)>=1>0 and w11*d^-w12>0 always).
    auto preRow = [&](v2f r, float* T, float* D, float* M, int i) {
        const float tt = r.x, rating = r.y;
        const float hb = (rating == 2.0f) ? w15
                       : ((rating == 4.0f) ? w16 : 1.0f);
        const float eh = (11.0f - dpre) * hb;
        const float m2 = w11 * __builtin_amdgcn_exp2f(
                             -w12 * __builtin_amdgcn_logf(dpre));
        M[i] = (rating > 1.0f) ? eh : -m2;
        const float nd = __builtin_fmaf(omw7, dpre,
                          __builtin_fmaf(-omw7w6, rating, dc0));
        dpre = fminf(fmaxf(nd, 1.0f), 10.0f);
        T[i] = tt;
        D[i] = dpre;
    };

    // s-chain row + NT store. Branch known up front (sign of M): one log
    // serves s^-w9 (success) and (s+1)^w13 (failure); u-v merges the
    // (A,e) algebra; clamps split per-branch (success can't underflow
    // S_MIN; failure can't exceed s<=S_MAX).
    auto stepRow = [&](float tt, float ms, float dd, int row) {
        const bool  sel = ms > 0.0f;                    // success?
        const float q   = __builtin_fmaf(9.0f, s, tt);  // 9s + t
        const float omr = tt * __builtin_amdgcn_rcpf(q);// 1 - r
        const float x   = omr * (sel ? w10l : w14l);
        const float ls  = __builtin_amdgcn_logf(sel ? s : (s + 1.0f));
        const float aa  = sel ? __builtin_fmaf(-w9, ls, w8l) : (w13 * ls);
        const float u   = __builtin_amdgcn_exp2f(aa + x);   // A*e
        const float v   = __builtin_amdgcn_exp2f(sel ? aa : x); // A or e
        const float m   = sel ? (ms * s) : (-ms);
        const float P   = (u - v) * m;
        const float su  = fminf(s + P, 36500.0f);
        const float fl  = fmaxf(fminf(P, s), 0.01f);
        s = sel ? su : fl;
        v2f o; o.x = s; o.y = dd;
        __builtin_nontemporal_store(o, &op[row * BATCH_N]);
    };

    // Prologue-only plain precompute of a chunk (no step material yet).
    auto preC = [&](const v2f* raw, float* T, float* D, float* M, int lo) {
#pragma unroll
        for (int i = 0; i < 16; ++i) {
            if (i < lo) continue;
            preRow(raw[i], T, D, M, i);
        }
    };

    // Fused phase: per row — load chunk lb row i into rawDst, preRow chunk
    // from rawSrc into (T2,D2,M2), step chunk sb row i from (T,D,M).
    auto fused = [&](const float* T, const float* D, const float* M,
                     int sb, int lo,
                     const v2f* rawSrc, float* T2, float* D2, float* M2,
                     bool doPre, v2f* rawDst, int lb, bool doLoad) {
#pragma unroll
        for (int i = 0; i < 16; ++i) {
            if (doLoad) rawDst[i] = ip[(lb + i) * BATCH_N];
            if (doPre)  preRow(rawSrc[i], T2, D2, M2, i);
            if (i >= lo) stepRow(T[i], M[i], D[i], sb + i);
        }
    };

    // ---- prologue: burst-load ch0, ch1; pre ch0; special row 0 ----
    loadC(rawA, 0);
    loadC(rawB, 16);

    const float r0 = rawA[0].y;
    {   // row 0: _first_step (d0 comes from rating only)
        const float d0 = fminf(fmaxf(
            __builtin_fmaf(-w5, r0 - 3.0f, w4), 1.0f), 10.0f);
        dpre = d0;
        tX[0] = rawA[0].x; dX[0] = d0; mX[0] = 1.0f;
    }
    preC(rawA, tX, dX, mX, 1);     // ch0 -> X; rawA free

    {   // step row 0 (special): s0 from weight table
        const float wsel = (r0 < 2.5f) ? ((r0 < 1.5f) ? w0 : w1)
                                       : ((r0 < 3.5f) ? w2 : w3);
        const float ns = (r0 >= 1.0f && r0 <= 4.0f) ? wsel : 1.0f;
        s = fminf(fmaxf(ns, 0.01f), 36500.0f);
        v2f o; o.x = s; o.y = dX[0];
        __builtin_nontemporal_store(o, &op[0]);
    }

    // fused(0): step ch0 rows 1..15 | pre ch1 (rawB->Y) | load ch2 -> rawA
    fused(tX, dX, mX, 0, 1, rawB, tY, dY, mY, true, rawA, 32, true);

    // ---- main: c covers k=2c+1 (odd) and k=2c+2 (even) ----
    // fused(odd k):  step Y (ch k) | pre rawA (ch k+1) -> X | load ch k+2 -> rawB
    // fused(even k): step X (ch k) | pre rawB (ch k+1) -> Y | load ch k+2 -> rawA
#pragma unroll 1
    for (int c = 0; c < 3; ++c) {
        fused(tY, dY, mY, 16 * (2 * c + 1), 0,
              rawA, tX, dX, mX, true, rawB, 16 * (2 * c + 3), true);
        fused(tX, dX, mX, 16 * (2 * c + 2), 0,
              rawB, tY, dY, mY, true, rawA, 16 * (2 * c + 4), c < 2);
    }

    // ---- tail: fused(7): step ch7 (Y) only — no pre, no load ----
    fused(tY, dY, mY, 112, 0, rawA, tX, dX, mX, false, rawB, 0, false);

    // final_state, appended after the (SEQ, BATCH) outputs.
    {
        v2f o; o.x = s; o.y = dY[15];
        op[SEQ_N * BATCH_N] = o;
    }
}

extern "C" void kernel_launch(void* const* d_in, const int* in_sizes, int n_in,
                              void* d_out, int out_size, void* d_ws, size_t ws_size,
                              hipStream_t stream) {
    const v2f*   in = (const v2f*)d_in[0];   // (128, 65536, 2) f32
    const float* w  = (const float*)d_in[1]; // (17,) f32
    v2f* out = (v2f*)d_out;                  // 128*65536 + 65536 float2
    fsrs_kernel<<<BATCH_N / 256, 256, 0, stream>>>(in, w, out);
}